// Round 11
// baseline (218.763 us; speedup 1.0000x reference)
//
#include <hip/hip_runtime.h>

typedef __attribute__((ext_vector_type(8))) short short8_t;  // 8 bf16 (4 VGPRs)
typedef __attribute__((ext_vector_type(4))) float float4_t;  // MFMA C/D
typedef unsigned short u16;
typedef unsigned int u32;
typedef unsigned long long u64;

// ---------- helpers ----------
__device__ inline u16 f2bf(float x) {
  union { float f; u32 u; } v; v.f = x;
  u32 r = v.u + 0x7FFFu + ((v.u >> 16) & 1u);  // round-to-nearest-even
  return (u16)(r >> 16);
}
#if __has_builtin(__builtin_amdgcn_cvt_pk_bf16_f32)
typedef __attribute__((ext_vector_type(2))) __bf16 bf162_t;
__device__ inline u32 pk2(float a, float b) {   // v_cvt_pk_bf16_f32: low=a, high=b, RNE
  union { bf162_t v; u32 u; } cv;
  cv.v = __builtin_amdgcn_cvt_pk_bf16_f32(a, b);
  return cv.u;
}
#else
__device__ inline u32 pk2(float a, float b) {
  return (u32)f2bf(a) | ((u32)f2bf(b) << 16);
}
#endif
__device__ inline short8_t cvt8(float4_t x0, float4_t x1) {
  union { u32 u[4]; short8_t v; } cv;
  cv.u[0] = pk2(x0[0], x0[1]);
  cv.u[1] = pk2(x0[2], x0[3]);
  cv.u[2] = pk2(x1[0], x1[1]);
  cv.u[3] = pk2(x1[2], x1[3]);
  return cv.v;
}

// ---------- prologue: W transposes only (X conversion fused into QKV GEMM) ----------
__global__ __launch_bounds__(256) void prologue(const float* __restrict__ Wq, const float* __restrict__ Wk,
                                                const float* __restrict__ Wv, const float* __restrict__ Wo,
                                                u16* __restrict__ WqkvT, u16* __restrict__ WoT) {
  __shared__ float tls[32][33];
  int t = blockIdx.x;
  int mat = t >> 10, tile = t & 1023;
  const float* W = (mat == 0) ? Wq : (mat == 1) ? Wk : (mat == 2) ? Wv : Wo;
  u16* WT = (mat < 3) ? WqkvT + ((size_t)mat << 20) : WoT;
  int tx = threadIdx.x & 31, ty = threadIdx.x >> 5;  // 32 x 8
  int c0 = (tile & 31) * 32, r0 = (tile >> 5) * 32;  // r0: k, c0: n
  #pragma unroll
  for (int i = 0; i < 4; ++i)
    tls[ty + i * 8][tx] = W[(r0 + ty + i * 8) * 1024 + c0 + tx];
  __syncthreads();
  #pragma unroll
  for (int i = 0; i < 4; ++i)
    WT[(size_t)(c0 + ty + i * 8) * 1024 + r0 + tx] = f2bf(tls[tx][ty + i * 8]);
}

// ---------- GEMM: 128x128 C-tile, 4 waves each 64x64, BK=64, VGPR-pipelined staging ----------
// Staging: global->VGPR->ds_write (barriers never drain global latency); linear global
// sources; XOR chunk swizzle at LDS DEST (ds_write/ds_read both 2-way = free).
// mode 4 (fused QKV, 768 blocks): A = fp32 X, converted to bf16 IN REGISTERS during
//   staging (prologue X round-trip eliminated). col block 0->Q(x0.125) o0 [B,H,S,64],
//   1->K o1, 2->V o2 [B,H,64,S] (transposed).
// mode 3 (O-proj, 256 blocks): A = bf16 Ctx, fp32 out o0.
__global__ __launch_bounds__(256) void gemm128(const u16* __restrict__ A, const float* __restrict__ Af,
                                               const u16* __restrict__ BT,
                                               const float* __restrict__ bias0, const float* __restrict__ bias1,
                                               const float* __restrict__ bias2,
                                               void* __restrict__ o0, void* __restrict__ o1, void* __restrict__ o2,
                                               int mode) {
  __shared__ __align__(16) u16 Als[128 * 64];  // 16 KB
  __shared__ __align__(16) u16 Bls[128 * 64];  // 16 KB
  int g = blockIdx.x, m0t, n0t;
  if (mode == 4) {  // 768 blocks: panels of 16 m-tiles x 24 n-tiles
    int mh = g / 384, r = g - mh * 384;
    n0t = r >> 4;
    m0t = mh * 16 + (r & 15);
  } else {          // 256 blocks
    m0t = g & 31;
    n0t = g >> 5;
  }
  const int m0 = m0t * 128, n0 = n0t * 128;
  const int lane = threadIdx.x & 63, wave = threadIdx.x >> 6;
  const int quad = lane >> 4, c = lane & 15;
  const int wm = wave >> 1, wn = wave & 1;

  // staging lanes: 8 rows x 8 chunks(16B bf16 / 32B fp32) per call
  const int srow = lane >> 3, schunk = lane & 7;
  int soff[4], dst[4];
  #pragma unroll
  for (int q = 0; q < 4; ++q) {
    int r = wave * 32 + q * 8 + srow;
    soff[q] = r * 1024 + (schunk << 3);                 // element index (linear)
    dst[q]  = r * 64 + ((schunk ^ (r & 7)) << 3);       // XOR-swizzled LDS dest
  }
  const u16* gA = A + (size_t)m0 * 1024;
  const float* gAf = Af + (size_t)m0 * 1024;
  const u16* gB = BT + (size_t)n0 * 1024;

  int ar[2][4], br[2][4];
  #pragma unroll
  for (int ko = 0; ko < 2; ++ko) {
    #pragma unroll
    for (int i = 0; i < 4; ++i) {
      int rowa = wm * 64 + i * 16 + c;
      ar[ko][i] = rowa * 64 + (((ko * 4 + quad) ^ (rowa & 7)) << 3);
      int rowb = wn * 64 + i * 16 + c;
      br[ko][i] = rowb * 64 + (((ko * 4 + quad) ^ (rowb & 7)) << 3);
    }
  }

  // prefetch slab 0 into VGPRs
  short8_t ra[4], rb[4];
  if (mode == 4) {
    #pragma unroll
    for (int q = 0; q < 4; ++q)
      ra[q] = cvt8(*(const float4_t*)(gAf + soff[q]), *(const float4_t*)(gAf + soff[q] + 4));
  } else {
    #pragma unroll
    for (int q = 0; q < 4; ++q) ra[q] = *(const short8_t*)(gA + soff[q]);
  }
  #pragma unroll
  for (int q = 0; q < 4; ++q) rb[q] = *(const short8_t*)(gB + soff[q]);

  float4_t acc[4][4] = {};
  for (int k0 = 0; k0 < 1024; k0 += 64) {
    // commit prefetched slab to LDS
    #pragma unroll
    for (int q = 0; q < 4; ++q) *(short8_t*)&Als[dst[q]] = ra[q];
    #pragma unroll
    for (int q = 0; q < 4; ++q) *(short8_t*)&Bls[dst[q]] = rb[q];
    __syncthreads();
    // issue next slab's loads now; latency hides under the 32 MFMAs below
    if (k0 < 960) {
      if (mode == 4) {
        #pragma unroll
        for (int q = 0; q < 4; ++q)
          ra[q] = cvt8(*(const float4_t*)(gAf + soff[q] + k0 + 64),
                       *(const float4_t*)(gAf + soff[q] + k0 + 68));
      } else {
        #pragma unroll
        for (int q = 0; q < 4; ++q) ra[q] = *(const short8_t*)(gA + soff[q] + k0 + 64);
      }
      #pragma unroll
      for (int q = 0; q < 4; ++q) rb[q] = *(const short8_t*)(gB + soff[q] + k0 + 64);
    }
    #pragma unroll
    for (int ko = 0; ko < 2; ++ko) {
      short8_t af[4], bfr[4];
      #pragma unroll
      for (int i = 0; i < 4; ++i) af[i] = *(const short8_t*)&Als[ar[ko][i]];
      #pragma unroll
      for (int j = 0; j < 4; ++j) bfr[j] = *(const short8_t*)&Bls[br[ko][j]];
      #pragma unroll
      for (int i = 0; i < 4; ++i)
        #pragma unroll
        for (int j = 0; j < 4; ++j)
          acc[i][j] = __builtin_amdgcn_mfma_f32_16x16x32_bf16(af[i], bfr[j], acc[i][j], 0, 0, 0);
    }
    __syncthreads();  // all reads done before next commit (single LDS buffer)
  }

  const int mrow = m0 + wm * 64, ncol = n0 + wn * 64;
  if (mode == 3) {
    float* o = (float*)o0;
    #pragma unroll
    for (int i = 0; i < 4; ++i) {
      #pragma unroll
      for (int j = 0; j < 4; ++j) {
        int colb = ncol + j * 16 + c;
        float bv = bias0[colb];
        int rowb = mrow + i * 16 + quad * 4;
        #pragma unroll
        for (int r = 0; r < 4; ++r)
          o[(size_t)(rowb + r) * 1024 + colb] = acc[i][j][r] + bv;
      }
    }
  } else {
    #pragma unroll
    for (int j = 0; j < 4; ++j) {
      int colb = ncol + j * 16 + c;     // 0..3071
      int which = colb >> 10;           // 0:Q 1:K 2:V (uniform per j)
      int n1 = colb & 1023, h = n1 >> 6, d = n1 & 63;
      const float* bp = (which == 0) ? bias0 : (which == 1 ? bias1 : bias2);
      float bv = bp[n1];
      #pragma unroll
      for (int i = 0; i < 4; ++i) {
        int rowb = mrow + i * 16 + quad * 4;
        int b = rowb >> 11, s = rowb & 2047;
        if (which == 2) {
          u16* o = (u16*)o2 + (((size_t)(b * 16 + h) * 64 + d) * 2048 + s);
          union { u32 u[2]; u64 ll; } ov;
          ov.u[0] = pk2(acc[i][j][0] + bv, acc[i][j][1] + bv);
          ov.u[1] = pk2(acc[i][j][2] + bv, acc[i][j][3] + bv);
          *(u64*)o = ov.ll;
        } else {
          float sc = (which == 0) ? 0.125f : 1.0f;
          u16* o = (u16*)((which == 0) ? o0 : o1);
          #pragma unroll
          for (int r = 0; r < 4; ++r)
            o[(((size_t)(b * 16 + h) * 2048 + (s + r)) << 6) + d] = f2bf((acc[i][j][r] + bv) * sc);
        }
      }
    }
  }
}

// P^T C-layout -> 16x16x32 B-operand layout via packed-bf16 shuffles (proven r2-r10)
__device__ inline short8_t p_to_b32(const float* p, int quad, int c) {
  u32 pk0[2] = {pk2(p[0], p[1]), pk2(p[2], p[3])};
  u32 pk1[2] = {pk2(p[4], p[5]), pk2(p[6], p[7])};
  int base = ((quad & 1) * 2) * 16 + c;
  union { u32 u[4]; short8_t v; } pf;
  #pragma unroll
  for (int x = 0; x < 4; ++x) {
    int src = base + ((x >> 1) << 4);
    int v0 = __shfl((int)pk0[x & 1], src);
    int v1 = __shfl((int)pk1[x & 1], src);
    pf.u[x] = (quad < 2) ? (u32)v0 : (u32)v1;
  }
  return pf.v;
}

// ---------- flash attention: 64-query tile per block, dbuf LDS, 1 barrier/tile ----------
// Q,K: [B,H,S,64] bf16 (Q pre-scaled 1/8); VT: [B,H,64,S]; ctx: [B,S,1024] bf16.
// Grid 1024 x 256. bh = (g&7)*4+((g>>3)&3) (XCD L2 affinity). qt mapping (r11 fix):
// under round-robin dispatch (g mod 256 ~ CU), a CU receives u in {v, v+8, v+16, v+24};
// map u<8 -> 31-u (heavy, FIRST), u<16 -> u-8, u<24 -> 39-u, else u-16 so each CU's
// 4-block set sums to 62 tiles with a heavy block resident from the start (r10's
// mapping put all 512 heavy blocks in the first wavefront of dispatch -> 2 long
// blocks/CU steady-state, 25% occupancy).
// 4 waves each own 16 queries. Per 64-key tile: K (64x64) and V^T (64x64) staged into
// the PARITY LDS buffer via VGPR prefetch -> ONE barrier per tile, no staging drain.
// Fixed-base softmax; causal select only on the diagonal tile.
__global__ __launch_bounds__(256, 4) void attn_kernel(const u16* __restrict__ Q, const u16* __restrict__ K,
                                                      const u16* __restrict__ VT, const float* __restrict__ mask,
                                                      u16* __restrict__ ctx) {
  __shared__ __align__(16) u16 Kls[2 * 64 * 64];  // 2 x 8 KB, [key][d] swizzled
  __shared__ __align__(16) u16 Vls[2 * 64 * 64];  // 2 x 8 KB, [d][key] swizzled
  const float C1 = 10000.0f * 1.4426950408889634f;
  const float LOG2E = 1.4426950408889634f;
  int w = threadIdx.x >> 6, lane = threadIdx.x & 63;
  int quad = lane >> 4, c = lane & 15;
  int g = blockIdx.x;
  int bh = (g & 7) * 4 + ((g >> 3) & 3);
  int u = g >> 5;                            // 0..31
  int qt = (u < 8) ? (31 - u) : (u < 16) ? (u - 8) : (u < 24) ? (39 - u) : (u - 16);
  int b = bh >> 4, h = bh & 15;
  const u16* Kp = K + ((size_t)bh << 17);
  const u16* Vp = VT + ((size_t)bh << 17);
  const float* mp = mask + (b << 11);
  int q0 = qt * 64 + w * 16;

  // Q^T B-operand fragment (16 queries per wave)
  const u16* Qp = Q + (((size_t)bh * 2048 + q0 + c) << 6) + quad * 8;
  short8_t qf0 = *(const short8_t*)(Qp);
  short8_t qf1 = *(const short8_t*)(Qp + 32);

  // staging: 64 rows x 8 chunks(16B) per tile; wave w covers rows w*16..+15 (2 calls)
  const int srow = lane >> 3, schunk = lane & 7;
  const u16* gK[2]; const u16* gV[2]; int dK[2], dV[2];
  #pragma unroll
  for (int i = 0; i < 2; ++i) {
    int R = w * 16 + i * 8 + srow;           // key row (K) / d row (V)
    gK[i] = Kp + R * 64 + (schunk << 3);                 // linear source
    dK[i] = R * 64 + ((schunk ^ (R & 7)) << 3);          // swizzled dest
    gV[i] = Vp + (size_t)R * 2048 + (schunk << 3);
    dV[i] = R * 64 + ((schunk ^ (R & 7)) << 3);
  }

  // fragment read offsets with matching swizzle
  int koff[4][2];
  #pragma unroll
  for (int kg = 0; kg < 4; ++kg) {
    int r = kg * 16 + c;
    #pragma unroll
    for (int ko = 0; ko < 2; ++ko)
      koff[kg][ko] = r * 64 + (((ko * 4 + quad) ^ (r & 7)) << 3);
  }
  int voff[4][2];
  #pragma unroll
  for (int dblk = 0; dblk < 4; ++dblk) {
    int d = dblk * 16 + c;
    #pragma unroll
    for (int kc = 0; kc < 2; ++kc)
      voff[dblk][kc] = d * 64 + (((kc * 4 + quad) ^ (d & 7)) << 3);
  }

  int ke[8];
  #pragma unroll
  for (int e = 0; e < 8; ++e) ke[e] = ((e >> 2) << 4) + quad * 4 + (e & 3);
  int thr = w * 16 + c;  // causal threshold within the diagonal tile

  float4_t O[4] = {};
  float l = 0.0f;

  // prefetch tile 0 into VGPRs
  short8_t kreg[2], vreg[2];
  #pragma unroll
  for (int i = 0; i < 2; ++i) { kreg[i] = *(const short8_t*)(gK[i]); vreg[i] = *(const short8_t*)(gV[i]); }

  for (int t = 0; t <= qt; ++t) {
    int kb = t << 6;
    int bufo = (t & 1) << 12;  // 4096 u16 per buffer
    #pragma unroll
    for (int i = 0; i < 2; ++i) *(short8_t*)&Kls[bufo + dK[i]] = kreg[i];
    #pragma unroll
    for (int i = 0; i < 2; ++i) *(short8_t*)&Vls[bufo + dV[i]] = vreg[i];
    __syncthreads();
    if (t < qt) {  // issue tile t+1 loads; land during this tile's compute
      int kb2 = (t + 1) << 6;
      #pragma unroll
      for (int i = 0; i < 2; ++i) {
        kreg[i] = *(const short8_t*)(gK[i] + (size_t)kb2 * 64);
        vreg[i] = *(const short8_t*)(gV[i] + kb2);
      }
    }
    // ---- S^T = K_tile @ Q^T (8 MFMA) ----
    float4_t s[4];
    #pragma unroll
    for (int kg = 0; kg < 4; ++kg) {
      short8_t k0 = *(const short8_t*)&Kls[bufo + koff[kg][0]];
      short8_t k1 = *(const short8_t*)&Kls[bufo + koff[kg][1]];
      float4_t a = {};
      a = __builtin_amdgcn_mfma_f32_16x16x32_bf16(k0, qf0, a, 0, 0, 0);
      a = __builtin_amdgcn_mfma_f32_16x16x32_bf16(k1, qf1, a, 0, 0, 0);
      s[kg] = a;
    }
    // ---- masks + fixed-base softmax + C->B transform ----
    float4_t mpl[4];
    #pragma unroll
    for (int kg = 0; kg < 4; ++kg)
      mpl[kg] = (*(const float4_t*)(mp + kb + kg * 16 + quad * 4) - 1.0f) * C1;
    bool diag = (t == qt);
    short8_t pf[2];
    #pragma unroll
    for (int kc = 0; kc < 2; ++kc) {
      float p[8];
      #pragma unroll
      for (int e = 0; e < 8; ++e) {
        int kg = kc * 2 + (e >> 2);
        p[e] = __builtin_fmaf(s[kg][e & 3], LOG2E, mpl[kg][e & 3]);
      }
      if (diag) {
        #pragma unroll
        for (int e = 0; e < 8; ++e) {
          int ko2 = kc * 32 + ke[e];
          p[e] = (ko2 > thr) ? -50.0f : p[e];
        }
      }
      #pragma unroll
      for (int e = 0; e < 8; ++e) {
        float pe = exp2f(p[e]);
        p[e] = pe;
        l += pe;
      }
      pf[kc] = p_to_b32(p, quad, c);
    }
    // ---- ctx^T += V^T_tile @ P^T (8 MFMA) ----
    #pragma unroll
    for (int dblk = 0; dblk < 4; ++dblk) {
      #pragma unroll
      for (int kc = 0; kc < 2; ++kc) {
        short8_t vf = *(const short8_t*)&Vls[bufo + voff[dblk][kc]];
        O[dblk] = __builtin_amdgcn_mfma_f32_16x16x32_bf16(vf, pf[kc], O[dblk], 0, 0, 0);
      }
    }
    // no trailing barrier: next tile writes the OTHER buffer; its leading barrier
    // orders those writes after every wave's reads of this buffer.
  }
  // ---- epilogue: reduce l across quads, normalize, store ----
  l += __shfl_xor(l, 16);
  l += __shfl_xor(l, 32);
  float rl = 1.0f / l;
  u16* op = ctx + ((size_t)(b * 2048 + q0 + c) * 1024 + h * 64 + quad * 4);
  #pragma unroll
  for (int dblk = 0; dblk < 4; ++dblk) {
    union { u32 uu[2]; u64 ll; } ov;
    ov.uu[0] = pk2(O[dblk][0] * rl, O[dblk][1] * rl);
    ov.uu[1] = pk2(O[dblk][2] * rl, O[dblk][3] * rl);
    *(u64*)(op + dblk * 16) = ov.ll;
  }
}

// ---------- launch ----------
extern "C" void kernel_launch(void* const* d_in, const int* in_sizes, int n_in,
                              void* d_out, int out_size, void* d_ws, size_t ws_size,
                              hipStream_t stream) {
  const float* X    = (const float*)d_in[0];
  const float* mask = (const float*)d_in[1];
  const float* Wq   = (const float*)d_in[2];
  const float* bq   = (const float*)d_in[3];
  const float* Wk   = (const float*)d_in[4];
  const float* bk   = (const float*)d_in[5];
  const float* Wv   = (const float*)d_in[6];
  const float* bv   = (const float*)d_in[7];
  const float* Wo   = (const float*)d_in[8];
  const float* bo   = (const float*)d_in[9];

  char* w = (char*)d_ws;
  u16* WqkvT  = (u16*)(w + (8ull  << 20)); // 6 MB  [3072,1024] bf16 (Q|K|V transposed)
  u16* WoT    = (u16*)(w + (14ull << 20)); // 2 MB  [1024,1024] bf16
  u16* Qb     = (u16*)(w + (16ull << 20)); // 8 MB [B,H,S,64]
  u16* Kb     = (u16*)(w + (24ull << 20)); // 8 MB [B,H,S,64]
  u16* VTb    = (u16*)(w + (32ull << 20)); // 8 MB [B,H,64,S]
  u16* Ctx    = (u16*)(w + (40ull << 20)); // 8 MB [4096,1024]

  prologue<<<4096, 256, 0, stream>>>(Wq, Wk, Wv, Wo, WqkvT, WoT);
  gemm128<<<768, 256, 0, stream>>>(nullptr, X, WqkvT, bq, bk, bv, Qb, Kb, VTb, 4);
  attn_kernel<<<1024, 256, 0, stream>>>(Qb, Kb, VTb, mask, Ctx);
  gemm128<<<256, 256, 0, stream>>>(Ctx, nullptr, WoT, bo, bo, bo, d_out, d_out, d_out, 3);
}